// Round 4
// baseline (512.449 us; speedup 1.0000x reference)
//
#include <hip/hip_runtime.h>
#include <hip/hip_bf16.h>

// Attention block: x[16,1024,768] -> QKV -> MHA(12 heads, d=64) -> proj.
// GEMMs: bf16 MFMA 16x16x32, global_load_lds width-16 staging (m97 pattern).
// Flash attention: no LDS, no barriers. S^T via operand-swapped MFMA so the
// exp2'd P is already in 16x16x16 A-operand layout (k=quad*4+j); K/V register
// ping-pong prefetch; row sums via ones-MFMA; Q pre-scaled by log2(e)/8.
// Workspace: same layout as R1/R2 (~131 MB).

#define EDIM 768
#define NH 12
#define HD 64
#define BB 16
#define SN 1024
#define MTOT (BB*SN)   // 16384

typedef __attribute__((ext_vector_type(8))) short short8;
typedef __attribute__((ext_vector_type(4))) short short4v;
typedef __attribute__((ext_vector_type(4))) float f32x4;
typedef unsigned short bfr;

// NOTE: __has_builtin on AMDGCN builtins is only meaningful in the DEVICE pass;
// the host pass has none of them (R3 failed by #error-ing in the host pass).
#if defined(__HIP_DEVICE_COMPILE__)
#if !__has_builtin(__builtin_amdgcn_mfma_f32_16x16x16bf16_1k)
#error "missing __builtin_amdgcn_mfma_f32_16x16x16bf16_1k on device"
#endif
#endif

#define MFMA32(A,B,C) __builtin_amdgcn_mfma_f32_16x16x32_bf16(A,B,C,0,0,0)
#define MFMA16(A,B,C) __builtin_amdgcn_mfma_f32_16x16x16bf16_1k(A,B,C,0,0,0)

__device__ __forceinline__ bfr f2bf(float f) {
    union { float f; unsigned int u; } v; v.f = f;
    unsigned int u = v.u;
    u += 0x7FFFu + ((u >> 16) & 1u);   // RNE
    return (bfr)(u >> 16);
}
__device__ __forceinline__ bfr f2bf_fast(float f) {
    union { float f; unsigned int u; } v; v.f = f;
    return (bfr)((v.u + 0x8000u) >> 16);
}

// async global->LDS, 16 bytes per lane; lds base must be wave-uniform.
__device__ __forceinline__ void gl2lds16(const bfr* g, bfr* l) {
    __builtin_amdgcn_global_load_lds(
        (__attribute__((address_space(1))) void*)(g),
        (__attribute__((address_space(3))) void*)(l), 16, 0, 0);
}

// ---------------- convert fp32 -> bf16 ----------------
__global__ void k_convert(const float* __restrict__ in, bfr* __restrict__ out, int n4) {
    int i = blockIdx.x * blockDim.x + threadIdx.x;
    if (i >= n4) return;
    float4 v = ((const float4*)in)[i];
    ushort4 o;
    o.x = f2bf(v.x); o.y = f2bf(v.y); o.z = f2bf(v.z); o.w = f2bf(v.w);
    ((ushort4*)out)[i] = o;
}

// ---------------- transpose + convert: in[R][C] fp32 -> out[C][R] bf16 ----------------
__global__ void k_transpose_bf16(const float* __restrict__ in, bfr* __restrict__ out,
                                 int R, int C) {
    __shared__ float tile[32][33];
    int c0 = blockIdx.x * 32, r0 = blockIdx.y * 32;
    int tx = threadIdx.x & 31, ty = threadIdx.x >> 5;
    #pragma unroll
    for (int i = 0; i < 32; i += 8)
        tile[ty + i][tx] = in[(size_t)(r0 + ty + i) * C + c0 + tx];
    __syncthreads();
    #pragma unroll
    for (int i = 0; i < 32; i += 8)
        out[(size_t)(c0 + ty + i) * R + r0 + tx] = f2bf(tile[tx][ty + i]);
}

// ---------------- bf16 MFMA GEMM: C[M,N] = A[M,768] @ BT[N,768]^T + bias ----------------
// Staging via global_load_lds (16B/lane), unpadded 128x32 LDS tiles.
#define QSCALE 0.18033688011112042f   // log2(e)/8
template <int EPI>
__launch_bounds__(256, 2)
__global__ void k_gemm_bt(const bfr* __restrict__ A, const bfr* __restrict__ BT,
                          const float* __restrict__ bias, float* __restrict__ out,
                          bfr* __restrict__ qb, bfr* __restrict__ kb, bfr* __restrict__ vT) {
    __shared__ bfr As[128 * 32];
    __shared__ bfr Bs[128 * 32];

    const int m0 = blockIdx.y * 128;
    const int n0 = blockIdx.x * 128;
    const int t = threadIdx.x;
    const int lane = t & 63;
    const int wave = t >> 6;
    const int wr = wave >> 1, wc = wave & 1;
    const int l15 = lane & 15, quad = lane >> 4;

    f32x4 acc[4][4] = {};

    // chunk id: each lane owns one 16B chunk per instruction; row=c>>2, col8=(c&3)*8
    const int c0 = wave * 64 + lane;
    const bfr* gA0 = A  + (size_t)(m0 + (c0 >> 2)) * 768 + (c0 & 3) * 8;
    const bfr* gA1 = A  + (size_t)(m0 + 64 + (c0 >> 2)) * 768 + (c0 & 3) * 8;
    const bfr* gB0 = BT + (size_t)(n0 + (c0 >> 2)) * 768 + (c0 & 3) * 8;
    const bfr* gB1 = BT + (size_t)(n0 + 64 + (c0 >> 2)) * 768 + (c0 & 3) * 8;
    bfr* lA0 = As + wave * 512;          // wave-uniform bases
    bfr* lA1 = As + 2048 + wave * 512;
    bfr* lB0 = Bs + wave * 512;
    bfr* lB1 = Bs + 2048 + wave * 512;

    for (int kt = 0; kt < 768; kt += 32) {
        __syncthreads();                 // prev iter's ds_reads complete
        gl2lds16(gA0 + kt, lA0);
        gl2lds16(gA1 + kt, lA1);
        gl2lds16(gB0 + kt, lB0);
        gl2lds16(gB1 + kt, lB1);
        __syncthreads();                 // drains vmcnt: LDS tiles ready

        short8 af[4], bf[4];
        #pragma unroll
        for (int rt = 0; rt < 4; rt++)
            af[rt] = *(const short8*)(As + (wr * 64 + rt * 16 + l15) * 32 + quad * 8);
        #pragma unroll
        for (int ct = 0; ct < 4; ct++)
            bf[ct] = *(const short8*)(Bs + (wc * 64 + ct * 16 + l15) * 32 + quad * 8);
        #pragma unroll
        for (int rt = 0; rt < 4; rt++)
            #pragma unroll
            for (int ct = 0; ct < 4; ct++)
                acc[rt][ct] = MFMA32(af[rt], bf[ct], acc[rt][ct]);
    }

    #pragma unroll
    for (int rt = 0; rt < 4; rt++) {
        #pragma unroll
        for (int ct = 0; ct < 4; ct++) {
            const int col = n0 + wc * 64 + ct * 16 + l15;
            const float bv = bias[col];
            #pragma unroll
            for (int reg = 0; reg < 4; reg++) {
                const int m = m0 + wr * 64 + rt * 16 + quad * 4 + reg;
                float val = acc[rt][ct][reg] + bv;
                if constexpr (EPI == 0) {
                    out[(size_t)m * EDIM + col] = val;
                } else {
                    const int three = col / 768;
                    const int rem = col - three * 768;
                    const int h = rem >> 6, d = rem & 63;
                    const int b = m >> 10, n = m & 1023;
                    const size_t bh = (size_t)b * NH + h;
                    if (three == 0)      qb[(bh * SN + n) * HD + d] = f2bf(val * QSCALE);
                    else if (three == 1) kb[(bh * SN + n) * HD + d] = f2bf(val);
                    else                 vT[(bh * HD + d) * SN + n] = f2bf(val);
                }
            }
        }
    }
}

// ---------------- flash attention: no LDS, no barriers, register pipeline ----------------
// Grid: (B*H, SN/128). Block: 4 waves; wave w owns q rows [w*32, w*32+32).
// S^T = mfma32(kf, qf) puts P in lane layout (q=l15, kv=quad*4+r) == A-frag of
// mfma 16x16x16 (k=quad*4+j): PV + row-sum MFMAs feed straight from registers.
struct KV { short8 kf[2][2]; short4v vf[2][4]; };

__device__ __forceinline__ void load_kv(const bfr* kbase, const bfr* vbase, int kv0,
                                        int l15, int quad, KV& o) {
    #pragma unroll
    for (int kvt = 0; kvt < 2; kvt++)
        #pragma unroll
        for (int c = 0; c < 2; c++)
            o.kf[kvt][c] = *(const short8*)(kbase + (size_t)(kv0 + kvt * 16 + l15) * HD + c * 32 + quad * 8);
    #pragma unroll
    for (int kvt = 0; kvt < 2; kvt++)
        #pragma unroll
        for (int ct = 0; ct < 4; ct++)
            o.vf[kvt][ct] = *(const short4v*)(vbase + (size_t)(ct * 16 + l15) * SN + kv0 + kvt * 16 + quad * 4);
}

__device__ __forceinline__ unsigned pkexp(float a, float b) {
    return (unsigned)f2bf_fast(exp2f(a)) | ((unsigned)f2bf_fast(exp2f(b)) << 16);
}

__device__ __forceinline__ void attn_step(const KV& kv, const short8 qf[2][2],
                                          f32x4 o_acc[2][4], f32x4 l_acc[2],
                                          short4v ones4) {
    f32x4 st[2][2] = {};   // st[kvt][qt]: S^T tile (rows kv, cols q)
    #pragma unroll
    for (int c = 0; c < 2; c++)
        #pragma unroll
        for (int kvt = 0; kvt < 2; kvt++)
            #pragma unroll
            for (int qt = 0; qt < 2; qt++)
                st[kvt][qt] = MFMA32(kv.kf[kvt][c], qf[qt][c], st[kvt][qt]);

    short4v pf[2][2];
    #pragma unroll
    for (int kvt = 0; kvt < 2; kvt++)
        #pragma unroll
        for (int qt = 0; qt < 2; qt++) {
            union { unsigned u[2]; short4v s; } cv;
            cv.u[0] = pkexp(st[kvt][qt][0], st[kvt][qt][1]);
            cv.u[1] = pkexp(st[kvt][qt][2], st[kvt][qt][3]);
            pf[kvt][qt] = cv.s;
        }

    #pragma unroll
    for (int kvt = 0; kvt < 2; kvt++)
        #pragma unroll
        for (int qt = 0; qt < 2; qt++)
            l_acc[qt] = MFMA16(pf[kvt][qt], ones4, l_acc[qt]);
    #pragma unroll
    for (int kvt = 0; kvt < 2; kvt++)
        #pragma unroll
        for (int qt = 0; qt < 2; qt++)
            #pragma unroll
            for (int ct = 0; ct < 4; ct++)
                o_acc[qt][ct] = MFMA16(pf[kvt][qt], kv.vf[kvt][ct], o_acc[qt][ct]);
}

__launch_bounds__(256, 3)
__global__ void k_attn(const bfr* __restrict__ qb, const bfr* __restrict__ kb,
                       const bfr* __restrict__ vT, bfr* __restrict__ ao) {
    const int bh = blockIdx.x;            // XCD swizzle: bh -> XCD bh%8
    const int q0 = blockIdx.y * 128;
    const int t = threadIdx.x;
    const int lane = t & 63, w = t >> 6;
    const int l15 = lane & 15, quad = lane >> 4;

    const bfr* qbase = qb + (size_t)bh * SN * HD;
    const bfr* kbase = kb + (size_t)bh * SN * HD;
    const bfr* vbase = vT + (size_t)bh * HD * SN;

    // Q B-frags for S^T: qf[qt][c], lane l15 = q row, k = d
    short8 qf[2][2];
    #pragma unroll
    for (int qt = 0; qt < 2; qt++)
        #pragma unroll
        for (int c = 0; c < 2; c++)
            qf[qt][c] = *(const short8*)(qbase + (size_t)(q0 + w * 32 + qt * 16 + l15) * HD + c * 32 + quad * 8);

    f32x4 o_acc[2][4] = {};
    f32x4 l_acc[2] = {};
    short4v ones4;
    #pragma unroll
    for (int i = 0; i < 4; i++) ones4[i] = (short)0x3F80;

    KV a, b;
    load_kv(kbase, vbase, 0, l15, quad, a);
    for (int kv0 = 0; kv0 < SN; kv0 += 64) {
        load_kv(kbase, vbase, kv0 + 32, l15, quad, b);
        attn_step(a, qf, o_acc, l_acc, ones4);
        if (kv0 + 64 < SN) load_kv(kbase, vbase, kv0 + 64, l15, quad, a);
        attn_step(b, qf, o_acc, l_acc, ones4);
    }

    const int bb = bh / NH, h = bh % NH;
    #pragma unroll
    for (int qt = 0; qt < 2; qt++) {
        #pragma unroll
        for (int r = 0; r < 4; r++) {
            const float inv = 1.0f / l_acc[qt][r];
            const int n = q0 + w * 32 + qt * 16 + quad * 4 + r;
            #pragma unroll
            for (int ct = 0; ct < 4; ct++) {
                const int d = ct * 16 + l15;
                ao[((size_t)bb * SN + n) * EDIM + h * HD + d] = f2bf_fast(o_acc[qt][ct][r] * inv);
            }
        }
    }
}

extern "C" void kernel_launch(void* const* d_in, const int* in_sizes, int n_in,
                              void* d_out, int out_size, void* d_ws, size_t ws_size,
                              hipStream_t stream) {
    const float* x      = (const float*)d_in[0];
    const float* w_qkv  = (const float*)d_in[1];
    const float* b_qkv  = (const float*)d_in[2];
    const float* w_proj = (const float*)d_in[3];
    const float* b_proj = (const float*)d_in[4];

    char* ws = (char*)d_ws;
    bfr* xb     = (bfr*)(ws + 0);
    bfr* wqkvT  = (bfr*)(ws + 25165824);
    bfr* wprojT = (bfr*)(ws + 28704768);
    bfr* qb     = (bfr*)(ws + 29884416);
    bfr* kb     = (bfr*)(ws + 55050240);
    bfr* vT     = (bfr*)(ws + 80216064);
    bfr* ao     = (bfr*)(ws + 105381888);

    k_convert<<<12288, 256, 0, stream>>>(x, xb, (MTOT * EDIM) / 4);
    k_transpose_bf16<<<dim3(2304 / 32, 768 / 32), 256, 0, stream>>>(w_qkv, wqkvT, 768, 2304);
    k_transpose_bf16<<<dim3(768 / 32, 768 / 32), 256, 0, stream>>>(w_proj, wprojT, 768, 768);
    k_gemm_bt<1><<<dim3(2304 / 128, MTOT / 128), 256, 0, stream>>>(
        xb, wqkvT, b_qkv, nullptr, qb, kb, vT);
    k_attn<<<dim3(BB * NH, SN / 128), 256, 0, stream>>>(qb, kb, vT, ao);
    k_gemm_bt<0><<<dim3(768 / 128, MTOT / 128), 256, 0, stream>>>(
        ao, wprojT, b_proj, (float*)d_out, nullptr, nullptr, nullptr);
}

// Round 5
// 341.110 us; speedup vs baseline: 1.5023x; 1.5023x over previous
//
#include <hip/hip_runtime.h>
#include <hip/hip_bf16.h>

// Attention block: x[16,1024,768] -> QKV -> MHA(12 heads, d=64) -> proj.
// GEMMs: bf16 MFMA 16x16x32, global_load_lds width-16 staging (m97 pattern).
// Flash attention (R5 hybrid): K/V staged cooperatively into double-buffered
// LDS (stride 72 = 9x16B, bank-friendly), ONE barrier per kv-iter; S^T via
// operand-swapped MFMA so exp2'd P stays register-resident in 16x16x16
// A-operand layout; row sums via ones-MFMA; Q pre-scaled by log2(e)/8.

#define EDIM 768
#define NH 12
#define HD 64
#define BB 16
#define SN 1024
#define MTOT (BB*SN)   // 16384

typedef __attribute__((ext_vector_type(8))) short short8;
typedef __attribute__((ext_vector_type(4))) short short4v;
typedef __attribute__((ext_vector_type(4))) float f32x4;
typedef unsigned short bfr;

// __has_builtin on AMDGCN builtins is only meaningful in the DEVICE pass.
#if defined(__HIP_DEVICE_COMPILE__)
#if !__has_builtin(__builtin_amdgcn_mfma_f32_16x16x16bf16_1k)
#error "missing __builtin_amdgcn_mfma_f32_16x16x16bf16_1k on device"
#endif
#endif

#define MFMA32(A,B,C) __builtin_amdgcn_mfma_f32_16x16x32_bf16(A,B,C,0,0,0)
#define MFMA16(A,B,C) __builtin_amdgcn_mfma_f32_16x16x16bf16_1k(A,B,C,0,0,0)

__device__ __forceinline__ bfr f2bf(float f) {
    union { float f; unsigned int u; } v; v.f = f;
    unsigned int u = v.u;
    u += 0x7FFFu + ((u >> 16) & 1u);   // RNE
    return (bfr)(u >> 16);
}
__device__ __forceinline__ bfr f2bf_fast(float f) {
    union { float f; unsigned int u; } v; v.f = f;
    return (bfr)((v.u + 0x8000u) >> 16);
}

// async global->LDS, 16 bytes per lane; lds base must be wave-uniform.
__device__ __forceinline__ void gl2lds16(const bfr* g, bfr* l) {
    __builtin_amdgcn_global_load_lds(
        (__attribute__((address_space(1))) void*)(g),
        (__attribute__((address_space(3))) void*)(l), 16, 0, 0);
}

// ---------------- convert fp32 -> bf16 ----------------
__global__ void k_convert(const float* __restrict__ in, bfr* __restrict__ out, int n4) {
    int i = blockIdx.x * blockDim.x + threadIdx.x;
    if (i >= n4) return;
    float4 v = ((const float4*)in)[i];
    ushort4 o;
    o.x = f2bf(v.x); o.y = f2bf(v.y); o.z = f2bf(v.z); o.w = f2bf(v.w);
    ((ushort4*)out)[i] = o;
}

// ---------------- transpose + convert: in[R][C] fp32 -> out[C][R] bf16 ----------------
__global__ void k_transpose_bf16(const float* __restrict__ in, bfr* __restrict__ out,
                                 int R, int C) {
    __shared__ float tile[32][33];
    int c0 = blockIdx.x * 32, r0 = blockIdx.y * 32;
    int tx = threadIdx.x & 31, ty = threadIdx.x >> 5;
    #pragma unroll
    for (int i = 0; i < 32; i += 8)
        tile[ty + i][tx] = in[(size_t)(r0 + ty + i) * C + c0 + tx];
    __syncthreads();
    #pragma unroll
    for (int i = 0; i < 32; i += 8)
        out[(size_t)(c0 + ty + i) * R + r0 + tx] = f2bf(tile[tx][ty + i]);
}

// ---------------- bf16 MFMA GEMM: C[M,N] = A[M,768] @ BT[N,768]^T + bias ----------------
#define QSCALE 0.18033688011112042f   // log2(e)/8
template <int EPI>
__launch_bounds__(256, 2)
__global__ void k_gemm_bt(const bfr* __restrict__ A, const bfr* __restrict__ BT,
                          const float* __restrict__ bias, float* __restrict__ out,
                          bfr* __restrict__ qb, bfr* __restrict__ kb, bfr* __restrict__ vT) {
    __shared__ bfr As[128 * 32];
    __shared__ bfr Bs[128 * 32];

    const int m0 = blockIdx.y * 128;
    const int n0 = blockIdx.x * 128;
    const int t = threadIdx.x;
    const int lane = t & 63;
    const int wave = t >> 6;
    const int wr = wave >> 1, wc = wave & 1;
    const int l15 = lane & 15, quad = lane >> 4;

    f32x4 acc[4][4] = {};

    const int c0 = wave * 64 + lane;
    const bfr* gA0 = A  + (size_t)(m0 + (c0 >> 2)) * 768 + (c0 & 3) * 8;
    const bfr* gA1 = A  + (size_t)(m0 + 64 + (c0 >> 2)) * 768 + (c0 & 3) * 8;
    const bfr* gB0 = BT + (size_t)(n0 + (c0 >> 2)) * 768 + (c0 & 3) * 8;
    const bfr* gB1 = BT + (size_t)(n0 + 64 + (c0 >> 2)) * 768 + (c0 & 3) * 8;
    bfr* lA0 = As + wave * 512;
    bfr* lA1 = As + 2048 + wave * 512;
    bfr* lB0 = Bs + wave * 512;
    bfr* lB1 = Bs + 2048 + wave * 512;

    for (int kt = 0; kt < 768; kt += 32) {
        __syncthreads();
        gl2lds16(gA0 + kt, lA0);
        gl2lds16(gA1 + kt, lA1);
        gl2lds16(gB0 + kt, lB0);
        gl2lds16(gB1 + kt, lB1);
        __syncthreads();

        short8 af[4], bf[4];
        #pragma unroll
        for (int rt = 0; rt < 4; rt++)
            af[rt] = *(const short8*)(As + (wr * 64 + rt * 16 + l15) * 32 + quad * 8);
        #pragma unroll
        for (int ct = 0; ct < 4; ct++)
            bf[ct] = *(const short8*)(Bs + (wc * 64 + ct * 16 + l15) * 32 + quad * 8);
        #pragma unroll
        for (int rt = 0; rt < 4; rt++)
            #pragma unroll
            for (int ct = 0; ct < 4; ct++)
                acc[rt][ct] = MFMA32(af[rt], bf[ct], acc[rt][ct]);
    }

    #pragma unroll
    for (int rt = 0; rt < 4; rt++) {
        #pragma unroll
        for (int ct = 0; ct < 4; ct++) {
            const int col = n0 + wc * 64 + ct * 16 + l15;
            const float bv = bias[col];
            #pragma unroll
            for (int reg = 0; reg < 4; reg++) {
                const int m = m0 + wr * 64 + rt * 16 + quad * 4 + reg;
                float val = acc[rt][ct][reg] + bv;
                if constexpr (EPI == 0) {
                    out[(size_t)m * EDIM + col] = val;
                } else {
                    const int three = col / 768;
                    const int rem = col - three * 768;
                    const int h = rem >> 6, d = rem & 63;
                    const int b = m >> 10, n = m & 1023;
                    const size_t bh = (size_t)b * NH + h;
                    if (three == 0)      qb[(bh * SN + n) * HD + d] = f2bf(val * QSCALE);
                    else if (three == 1) kb[(bh * SN + n) * HD + d] = f2bf(val);
                    else                 vT[(bh * HD + d) * SN + n] = f2bf(val);
                }
            }
        }
    }
}

// ---------------- flash attention (R5): LDS-staged K/V, register-resident P ----------------
// Grid: (B*H, SN/128). Block 256 = 4 waves; wave w owns q rows [w*32, w*32+32).
// Per 64-kv iter: cooperative stage K[64][64] + V^T[64][64] into LDS (stride 72),
// ONE barrier; S^T = mfma32(kf, qf) -> p = exp2 -> pf (A-frag of mfma16);
// l += mfma16(pf, ones); O += mfma16(pf, vf).
#define LDK 72   // 144B row stride = 9 x 16B: aligned b128, conflict-light

__launch_bounds__(256, 2)
__global__ void k_attn(const bfr* __restrict__ qb, const bfr* __restrict__ kb,
                       const bfr* __restrict__ vT, bfr* __restrict__ ao) {
    __shared__ bfr Ks[2][64 * LDK];
    __shared__ bfr Vs[2][64 * LDK];

    const int bh = blockIdx.x;            // bh fastest -> XCD L2 locality
    const int q0 = blockIdx.y * 128;
    const int t = threadIdx.x;
    const int lane = t & 63, w = t >> 6;
    const int l15 = lane & 15, quad = lane >> 4;

    const bfr* qbase = qb + (size_t)bh * SN * HD;
    const bfr* kbase = kb + (size_t)bh * SN * HD;
    const bfr* vbase = vT + (size_t)bh * HD * SN;

    // Q B-frags (S^T): qf[qt][c] at rows q0+w*32+qt*16+l15, k = c*32+quad*8
    short8 qf[2][2];
    #pragma unroll
    for (int qt = 0; qt < 2; qt++)
        #pragma unroll
        for (int c = 0; c < 2; c++)
            qf[qt][c] = *(const short8*)(qbase + (size_t)(q0 + w * 32 + qt * 16 + l15) * HD + c * 32 + quad * 8);

    f32x4 o_acc[2][4] = {};
    f32x4 l_acc[2] = {};
    short4v ones4;
    #pragma unroll
    for (int i = 0; i < 4; i++) ones4[i] = (short)0x3F80;

    // staging indices: thread t -> row t>>2 (0..63), col chunk (t&3)*16
    const int srow = t >> 2;
    const int scol = (t & 3) * 16;
    const bfr* gK = kbase + (size_t)srow * HD + scol;   // K tile region is contiguous
    const bfr* gV = vbase + (size_t)srow * SN + scol;   // V^T rows, SN apart
    const int soff = srow * LDK + scol;

    uint4 kr0, kr1, vr0, vr1;
    // preload iter 0
    kr0 = *(const uint4*)(gK);      kr1 = *(const uint4*)(gK + 8);
    vr0 = *(const uint4*)(gV);      vr1 = *(const uint4*)(gV + 8);
    *(uint4*)(&Ks[0][soff]) = kr0;  *(uint4*)(&Ks[0][soff + 8]) = kr1;
    *(uint4*)(&Vs[0][soff]) = vr0;  *(uint4*)(&Vs[0][soff + 8]) = vr1;

    for (int it = 0; it < SN / 64; it++) {
        const int cur = it & 1;
        const int kv0n = (it + 1) * 64;
        if (kv0n < SN) {   // prefetch next tile to registers (before the barrier)
            kr0 = *(const uint4*)(gK + (size_t)kv0n * HD);
            kr1 = *(const uint4*)(gK + (size_t)kv0n * HD + 8);
            vr0 = *(const uint4*)(gV + kv0n);
            vr1 = *(const uint4*)(gV + kv0n + 8);
        }
        __syncthreads();   // buf[cur] stores visible; prev compute on buf[cur^1] done
        if (kv0n < SN) {
            *(uint4*)(&Ks[cur ^ 1][soff]) = kr0;  *(uint4*)(&Ks[cur ^ 1][soff + 8]) = kr1;
            *(uint4*)(&Vs[cur ^ 1][soff]) = vr0;  *(uint4*)(&Vs[cur ^ 1][soff + 8]) = vr1;
        }

        const bfr* Kc = &Ks[cur][0];
        const bfr* Vc = &Vs[cur][0];

        // K A-frags: m=kv (l15 within 16-tile), k=d
        short8 kf[4][2];
        #pragma unroll
        for (int kvt = 0; kvt < 4; kvt++)
            #pragma unroll
            for (int c = 0; c < 2; c++)
                kf[kvt][c] = *(const short8*)(Kc + (kvt * 16 + l15) * LDK + c * 32 + quad * 8);
        // V B-frags (mfma16): n=d (l15), k=kv=quad*4+j
        short4v vf[4][4];
        #pragma unroll
        for (int kvt = 0; kvt < 4; kvt++)
            #pragma unroll
            for (int ct = 0; ct < 4; ct++)
                vf[kvt][ct] = *(const short4v*)(Vc + (ct * 16 + l15) * LDK + kvt * 16 + quad * 4);

        // S^T tiles: rows kv, cols q
        f32x4 st[4][2] = {};
        #pragma unroll
        for (int c = 0; c < 2; c++)
            #pragma unroll
            for (int kvt = 0; kvt < 4; kvt++)
                #pragma unroll
                for (int qt = 0; qt < 2; qt++)
                    st[kvt][qt] = MFMA32(kf[kvt][c], qf[qt][c], st[kvt][qt]);

        // p = exp2(s) packed to bf16 pairs -> A-frags of mfma16 (k=quad*4+j)
        short4v pf[4][2];
        #pragma unroll
        for (int kvt = 0; kvt < 4; kvt++)
            #pragma unroll
            for (int qt = 0; qt < 2; qt++) {
                union { unsigned u[2]; short4v s; } cv;
                cv.u[0] = (unsigned)f2bf_fast(exp2f(st[kvt][qt][0]))
                        | ((unsigned)f2bf_fast(exp2f(st[kvt][qt][1])) << 16);
                cv.u[1] = (unsigned)f2bf_fast(exp2f(st[kvt][qt][2]))
                        | ((unsigned)f2bf_fast(exp2f(st[kvt][qt][3])) << 16);
                pf[kvt][qt] = cv.s;
            }

        #pragma unroll
        for (int kvt = 0; kvt < 4; kvt++)
            #pragma unroll
            for (int qt = 0; qt < 2; qt++)
                l_acc[qt] = MFMA16(pf[kvt][qt], ones4, l_acc[qt]);
        #pragma unroll
        for (int kvt = 0; kvt < 4; kvt++)
            #pragma unroll
            for (int qt = 0; qt < 2; qt++)
                #pragma unroll
                for (int ct = 0; ct < 4; ct++)
                    o_acc[qt][ct] = MFMA16(pf[kvt][qt], vf[kvt][ct], o_acc[qt][ct]);
    }

    // normalize + write bf16 to ao[b, n, h*64+d]
    const int bb = bh / NH, h = bh % NH;
    #pragma unroll
    for (int qt = 0; qt < 2; qt++) {
        #pragma unroll
        for (int r = 0; r < 4; r++) {
            const float inv = 1.0f / l_acc[qt][r];
            const int n = q0 + w * 32 + qt * 16 + quad * 4 + r;
            #pragma unroll
            for (int ct = 0; ct < 4; ct++) {
                const int d = ct * 16 + l15;
                ao[((size_t)bb * SN + n) * EDIM + h * HD + d] = f2bf_fast(o_acc[qt][ct][r] * inv);
            }
        }
    }
}

extern "C" void kernel_launch(void* const* d_in, const int* in_sizes, int n_in,
                              void* d_out, int out_size, void* d_ws, size_t ws_size,
                              hipStream_t stream) {
    const float* x      = (const float*)d_in[0];
    const float* w_qkv  = (const float*)d_in[1];
    const float* b_qkv  = (const float*)d_in[2];
    const float* w_proj = (const float*)d_in[3];
    const float* b_proj = (const float*)d_in[4];

    char* ws = (char*)d_ws;
    bfr* xb     = (bfr*)(ws + 0);
    bfr* wqkvT  = (bfr*)(ws + 25165824);
    bfr* wprojT = (bfr*)(ws + 28704768);
    bfr* qb     = (bfr*)(ws + 29884416);
    bfr* kb     = (bfr*)(ws + 55050240);
    bfr* vT     = (bfr*)(ws + 80216064);
    bfr* ao     = (bfr*)(ws + 105381888);

    k_convert<<<12288, 256, 0, stream>>>(x, xb, (MTOT * EDIM) / 4);
    k_transpose_bf16<<<dim3(2304 / 32, 768 / 32), 256, 0, stream>>>(w_qkv, wqkvT, 768, 2304);
    k_transpose_bf16<<<dim3(768 / 32, 768 / 32), 256, 0, stream>>>(w_proj, wprojT, 768, 768);
    k_gemm_bt<1><<<dim3(2304 / 128, MTOT / 128), 256, 0, stream>>>(
        xb, wqkvT, b_qkv, nullptr, qb, kb, vT);
    k_attn<<<dim3(BB * NH, SN / 128), 256, 0, stream>>>(qb, kb, vT, ao);
    k_gemm_bt<0><<<dim3(768 / 128, MTOT / 128), 256, 0, stream>>>(
        ao, wprojT, b_proj, (float*)d_out, nullptr, nullptr, nullptr);
}

// Round 6
// 339.814 us; speedup vs baseline: 1.5080x; 1.0038x over previous
//
#include <hip/hip_runtime.h>
#include <hip/hip_bf16.h>

// Attention block: x[16,1024,768] -> QKV -> MHA(12 heads, d=64) -> proj.
// GEMMs: bf16 MFMA 16x16x32, global_load_lds width-16 staging, BK=64 as two
// sequential BK=32 slabs (R5 layout per slab) -> 32 MFMA per barrier pair.
// Flash attention (R5 hybrid, unchanged): K/V double-buffered LDS, one barrier
// per 64-kv iter, S^T operand-swap -> register-resident P in 16x16x16 A-layout,
// ones-MFMA row sums, Q pre-scaled by log2(e)/8.

#define EDIM 768
#define NH 12
#define HD 64
#define BB 16
#define SN 1024
#define MTOT (BB*SN)   // 16384

typedef __attribute__((ext_vector_type(8))) short short8;
typedef __attribute__((ext_vector_type(4))) short short4v;
typedef __attribute__((ext_vector_type(4))) float f32x4;
typedef unsigned short bfr;

// __has_builtin on AMDGCN builtins is only meaningful in the DEVICE pass.
#if defined(__HIP_DEVICE_COMPILE__)
#if !__has_builtin(__builtin_amdgcn_mfma_f32_16x16x16bf16_1k)
#error "missing __builtin_amdgcn_mfma_f32_16x16x16bf16_1k on device"
#endif
#endif

#define MFMA32(A,B,C) __builtin_amdgcn_mfma_f32_16x16x32_bf16(A,B,C,0,0,0)
#define MFMA16(A,B,C) __builtin_amdgcn_mfma_f32_16x16x16bf16_1k(A,B,C,0,0,0)

__device__ __forceinline__ bfr f2bf(float f) {
    union { float f; unsigned int u; } v; v.f = f;
    unsigned int u = v.u;
    u += 0x7FFFu + ((u >> 16) & 1u);   // RNE
    return (bfr)(u >> 16);
}
__device__ __forceinline__ bfr f2bf_fast(float f) {
    union { float f; unsigned int u; } v; v.f = f;
    return (bfr)((v.u + 0x8000u) >> 16);
}

// async global->LDS, 16 bytes per lane; lds base must be wave-uniform.
__device__ __forceinline__ void gl2lds16(const bfr* g, bfr* l) {
    __builtin_amdgcn_global_load_lds(
        (__attribute__((address_space(1))) void*)(g),
        (__attribute__((address_space(3))) void*)(l), 16, 0, 0);
}

// ---------------- convert fp32 -> bf16 ----------------
__global__ void k_convert(const float* __restrict__ in, bfr* __restrict__ out, int n4) {
    int i = blockIdx.x * blockDim.x + threadIdx.x;
    if (i >= n4) return;
    float4 v = ((const float4*)in)[i];
    ushort4 o;
    o.x = f2bf(v.x); o.y = f2bf(v.y); o.z = f2bf(v.z); o.w = f2bf(v.w);
    ((ushort4*)out)[i] = o;
}

// ---------------- transpose + convert: in[R][C] fp32 -> out[C][R] bf16 ----------------
__global__ void k_transpose_bf16(const float* __restrict__ in, bfr* __restrict__ out,
                                 int R, int C) {
    __shared__ float tile[32][33];
    int c0 = blockIdx.x * 32, r0 = blockIdx.y * 32;
    int tx = threadIdx.x & 31, ty = threadIdx.x >> 5;
    #pragma unroll
    for (int i = 0; i < 32; i += 8)
        tile[ty + i][tx] = in[(size_t)(r0 + ty + i) * C + c0 + tx];
    __syncthreads();
    #pragma unroll
    for (int i = 0; i < 32; i += 8)
        out[(size_t)(c0 + ty + i) * R + r0 + tx] = f2bf(tile[tx][ty + i]);
}

// ---------------- bf16 MFMA GEMM: C[M,N] = A[M,768] @ BT[N,768]^T + bias ----------------
// BK=64 per barrier pair, stored as two BK=32 slabs with the R5 layout each.
#define QSCALE 0.18033688011112042f   // log2(e)/8
template <int EPI>
__launch_bounds__(256, 3)
__global__ void k_gemm_bt(const bfr* __restrict__ A, const bfr* __restrict__ BT,
                          const float* __restrict__ bias, float* __restrict__ out,
                          bfr* __restrict__ qb, bfr* __restrict__ kb, bfr* __restrict__ vT) {
    __shared__ bfr As[2][128 * 32];   // [k-half][row*32 + col]
    __shared__ bfr Bs[2][128 * 32];

    const int m0 = blockIdx.y * 128;
    const int n0 = blockIdx.x * 128;
    const int t = threadIdx.x;
    const int lane = t & 63;
    const int wave = t >> 6;
    const int wr = wave >> 1, wc = wave & 1;
    const int l15 = lane & 15, quad = lane >> 4;

    f32x4 acc[4][4] = {};

    // staging map (per instruction): chunk = wave*64+lane; row=chunk>>2, col8=(chunk&3)*8
    const int c0 = wave * 64 + lane;
    const bfr* gA0 = A  + (size_t)(m0 + (c0 >> 2)) * 768 + (c0 & 3) * 8;
    const bfr* gA1 = A  + (size_t)(m0 + 64 + (c0 >> 2)) * 768 + (c0 & 3) * 8;
    const bfr* gB0 = BT + (size_t)(n0 + (c0 >> 2)) * 768 + (c0 & 3) * 8;
    const bfr* gB1 = BT + (size_t)(n0 + 64 + (c0 >> 2)) * 768 + (c0 & 3) * 8;
    const int w512 = wave * 512;

    for (int kt = 0; kt < 768; kt += 64) {
        __syncthreads();                 // prev iter's ds_reads complete
        #pragma unroll
        for (int kh = 0; kh < 2; kh++) {
            const int ko = kt + kh * 32;
            gl2lds16(gA0 + ko, &As[kh][w512]);
            gl2lds16(gA1 + ko, &As[kh][2048 + w512]);
            gl2lds16(gB0 + ko, &Bs[kh][w512]);
            gl2lds16(gB1 + ko, &Bs[kh][2048 + w512]);
        }
        __syncthreads();                 // vmcnt drained: both slabs ready

        #pragma unroll
        for (int kh = 0; kh < 2; kh++) {
            short8 af[4], bf[4];
            #pragma unroll
            for (int rt = 0; rt < 4; rt++)
                af[rt] = *(const short8*)(&As[kh][(wr * 64 + rt * 16 + l15) * 32 + quad * 8]);
            #pragma unroll
            for (int ct = 0; ct < 4; ct++)
                bf[ct] = *(const short8*)(&Bs[kh][(wc * 64 + ct * 16 + l15) * 32 + quad * 8]);
            #pragma unroll
            for (int rt = 0; rt < 4; rt++)
                #pragma unroll
                for (int ct = 0; ct < 4; ct++)
                    acc[rt][ct] = MFMA32(af[rt], bf[ct], acc[rt][ct]);
        }
    }

    #pragma unroll
    for (int rt = 0; rt < 4; rt++) {
        #pragma unroll
        for (int ct = 0; ct < 4; ct++) {
            const int col = n0 + wc * 64 + ct * 16 + l15;
            const float bv = bias[col];
            #pragma unroll
            for (int reg = 0; reg < 4; reg++) {
                const int m = m0 + wr * 64 + rt * 16 + quad * 4 + reg;
                float val = acc[rt][ct][reg] + bv;
                if constexpr (EPI == 0) {
                    out[(size_t)m * EDIM + col] = val;
                } else {
                    const int three = col / 768;
                    const int rem = col - three * 768;
                    const int h = rem >> 6, d = rem & 63;
                    const int b = m >> 10, n = m & 1023;
                    const size_t bh = (size_t)b * NH + h;
                    if (three == 0)      qb[(bh * SN + n) * HD + d] = f2bf(val * QSCALE);
                    else if (three == 1) kb[(bh * SN + n) * HD + d] = f2bf(val);
                    else                 vT[(bh * HD + d) * SN + n] = f2bf(val);
                }
            }
        }
    }
}

// ---------------- flash attention (R5): LDS-staged K/V, register-resident P ----------------
#define LDK 72   // 144B row stride = 9 x 16B: aligned b128, conflict-light

__launch_bounds__(256, 2)
__global__ void k_attn(const bfr* __restrict__ qb, const bfr* __restrict__ kb,
                       const bfr* __restrict__ vT, bfr* __restrict__ ao) {
    __shared__ bfr Ks[2][64 * LDK];
    __shared__ bfr Vs[2][64 * LDK];

    const int bh = blockIdx.x;            // bh fastest -> XCD L2 locality
    const int q0 = blockIdx.y * 128;
    const int t = threadIdx.x;
    const int lane = t & 63, w = t >> 6;
    const int l15 = lane & 15, quad = lane >> 4;

    const bfr* qbase = qb + (size_t)bh * SN * HD;
    const bfr* kbase = kb + (size_t)bh * SN * HD;
    const bfr* vbase = vT + (size_t)bh * HD * SN;

    short8 qf[2][2];
    #pragma unroll
    for (int qt = 0; qt < 2; qt++)
        #pragma unroll
        for (int c = 0; c < 2; c++)
            qf[qt][c] = *(const short8*)(qbase + (size_t)(q0 + w * 32 + qt * 16 + l15) * HD + c * 32 + quad * 8);

    f32x4 o_acc[2][4] = {};
    f32x4 l_acc[2] = {};
    short4v ones4;
    #pragma unroll
    for (int i = 0; i < 4; i++) ones4[i] = (short)0x3F80;

    const int srow = t >> 2;
    const int scol = (t & 3) * 16;
    const bfr* gK = kbase + (size_t)srow * HD + scol;
    const bfr* gV = vbase + (size_t)srow * SN + scol;
    const int soff = srow * LDK + scol;

    uint4 kr0, kr1, vr0, vr1;
    kr0 = *(const uint4*)(gK);      kr1 = *(const uint4*)(gK + 8);
    vr0 = *(const uint4*)(gV);      vr1 = *(const uint4*)(gV + 8);
    *(uint4*)(&Ks[0][soff]) = kr0;  *(uint4*)(&Ks[0][soff + 8]) = kr1;
    *(uint4*)(&Vs[0][soff]) = vr0;  *(uint4*)(&Vs[0][soff + 8]) = vr1;

    for (int it = 0; it < SN / 64; it++) {
        const int cur = it & 1;
        const int kv0n = (it + 1) * 64;
        if (kv0n < SN) {
            kr0 = *(const uint4*)(gK + (size_t)kv0n * HD);
            kr1 = *(const uint4*)(gK + (size_t)kv0n * HD + 8);
            vr0 = *(const uint4*)(gV + kv0n);
            vr1 = *(const uint4*)(gV + kv0n + 8);
        }
        __syncthreads();
        if (kv0n < SN) {
            *(uint4*)(&Ks[cur ^ 1][soff]) = kr0;  *(uint4*)(&Ks[cur ^ 1][soff + 8]) = kr1;
            *(uint4*)(&Vs[cur ^ 1][soff]) = vr0;  *(uint4*)(&Vs[cur ^ 1][soff + 8]) = vr1;
        }

        const bfr* Kc = &Ks[cur][0];
        const bfr* Vc = &Vs[cur][0];

        short8 kf[4][2];
        #pragma unroll
        for (int kvt = 0; kvt < 4; kvt++)
            #pragma unroll
            for (int c = 0; c < 2; c++)
                kf[kvt][c] = *(const short8*)(Kc + (kvt * 16 + l15) * LDK + c * 32 + quad * 8);
        short4v vf[4][4];
        #pragma unroll
        for (int kvt = 0; kvt < 4; kvt++)
            #pragma unroll
            for (int ct = 0; ct < 4; ct++)
                vf[kvt][ct] = *(const short4v*)(Vc + (ct * 16 + l15) * LDK + kvt * 16 + quad * 4);

        f32x4 st[4][2] = {};
        #pragma unroll
        for (int c = 0; c < 2; c++)
            #pragma unroll
            for (int kvt = 0; kvt < 4; kvt++)
                #pragma unroll
                for (int qt = 0; qt < 2; qt++)
                    st[kvt][qt] = MFMA32(kf[kvt][c], qf[qt][c], st[kvt][qt]);

        short4v pf[4][2];
        #pragma unroll
        for (int kvt = 0; kvt < 4; kvt++)
            #pragma unroll
            for (int qt = 0; qt < 2; qt++) {
                union { unsigned u[2]; short4v s; } cv;
                cv.u[0] = (unsigned)f2bf_fast(exp2f(st[kvt][qt][0]))
                        | ((unsigned)f2bf_fast(exp2f(st[kvt][qt][1])) << 16);
                cv.u[1] = (unsigned)f2bf_fast(exp2f(st[kvt][qt][2]))
                        | ((unsigned)f2bf_fast(exp2f(st[kvt][qt][3])) << 16);
                pf[kvt][qt] = cv.s;
            }

        #pragma unroll
        for (int kvt = 0; kvt < 4; kvt++)
            #pragma unroll
            for (int qt = 0; qt < 2; qt++)
                l_acc[qt] = MFMA16(pf[kvt][qt], ones4, l_acc[qt]);
        #pragma unroll
        for (int kvt = 0; kvt < 4; kvt++)
            #pragma unroll
            for (int qt = 0; qt < 2; qt++)
                #pragma unroll
                for (int ct = 0; ct < 4; ct++)
                    o_acc[qt][ct] = MFMA16(pf[kvt][qt], vf[kvt][ct], o_acc[qt][ct]);
    }

    const int bb = bh / NH, h = bh % NH;
    #pragma unroll
    for (int qt = 0; qt < 2; qt++) {
        #pragma unroll
        for (int r = 0; r < 4; r++) {
            const float inv = 1.0f / l_acc[qt][r];
            const int n = q0 + w * 32 + qt * 16 + quad * 4 + r;
            #pragma unroll
            for (int ct = 0; ct < 4; ct++) {
                const int d = ct * 16 + l15;
                ao[((size_t)bb * SN + n) * EDIM + h * HD + d] = f2bf_fast(o_acc[qt][ct][r] * inv);
            }
        }
    }
}

extern "C" void kernel_launch(void* const* d_in, const int* in_sizes, int n_in,
                              void* d_out, int out_size, void* d_ws, size_t ws_size,
                              hipStream_t stream) {
    const float* x      = (const float*)d_in[0];
    const float* w_qkv  = (const float*)d_in[1];
    const float* b_qkv  = (const float*)d_in[2];
    const float* w_proj = (const float*)d_in[3];
    const float* b_proj = (const float*)d_in[4];

    char* ws = (char*)d_ws;
    bfr* xb     = (bfr*)(ws + 0);
    bfr* wqkvT  = (bfr*)(ws + 25165824);
    bfr* wprojT = (bfr*)(ws + 28704768);
    bfr* qb     = (bfr*)(ws + 29884416);
    bfr* kb     = (bfr*)(ws + 55050240);
    bfr* vT     = (bfr*)(ws + 80216064);
    bfr* ao     = (bfr*)(ws + 105381888);

    k_convert<<<12288, 256, 0, stream>>>(x, xb, (MTOT * EDIM) / 4);
    k_transpose_bf16<<<dim3(2304 / 32, 768 / 32), 256, 0, stream>>>(w_qkv, wqkvT, 768, 2304);
    k_transpose_bf16<<<dim3(768 / 32, 768 / 32), 256, 0, stream>>>(w_proj, wprojT, 768, 768);
    k_gemm_bt<1><<<dim3(2304 / 128, MTOT / 128), 256, 0, stream>>>(
        xb, wqkvT, b_qkv, nullptr, qb, kb, vT);
    k_attn<<<dim3(BB * NH, SN / 128), 256, 0, stream>>>(qb, kb, vT, ao);
    k_gemm_bt<0><<<dim3(768 / 128, MTOT / 128), 256, 0, stream>>>(
        ao, wprojT, b_proj, (float*)d_out, nullptr, nullptr, nullptr);
}